// Round 10
// baseline (1230.217 us; speedup 1.0000x reference)
//
#include <hip/hip_runtime.h>
#include <hip/hip_bf16.h>
#include <cstdint>
#include <cstddef>

#define N_NODES 65536
#define N_EDGES 1048576
#define N_GRAPHS 128
#define NPG 512
#define IN_DIM 64
#define HID 128
#define BN_EPS 1e-5f

typedef __attribute__((ext_vector_type(8))) short bf16x8;
typedef __attribute__((ext_vector_type(4))) float f32x4;
typedef __attribute__((ext_vector_type(8))) unsigned short u16x8;
typedef __attribute__((ext_vector_type(4))) unsigned short u16x4;

// ---- bf16 helpers (RNE, matches v_cvt) ----
__device__ inline unsigned short f2bf(float f) {
  unsigned u = __builtin_bit_cast(unsigned, f);
  u = u + 0x7fffu + ((u >> 16) & 1u);
  return (unsigned short)(u >> 16);
}
__device__ inline float bf2f(unsigned short h) {
  unsigned u = ((unsigned)h) << 16;
  return __builtin_bit_cast(float, u);
}
__device__ inline void split_bf(float v, unsigned short& hi, unsigned short& lo) {
  hi = f2bf(v);
  lo = f2bf(v - bf2f(hi));
}
// 8-B-aligned LDS fragment load (two ds_read_b64) — rows stride 36 u16 = 72 B
__device__ inline bf16x8 ld_bf8(const unsigned short* p) {
  u16x4 a = *(const u16x4*)p;
  u16x4 b = *(const u16x4*)(p + 4);
  u16x8 r = __builtin_shufflevector(a, b, 0, 1, 2, 3, 4, 5, 6, 7);
  return __builtin_bit_cast(bf16x8, r);
}

// ---------------- CSR build ----------------
__global__ __launch_bounds__(256) void hist_kernel(const int* __restrict__ dst,
                                                   int* __restrict__ deg) {
  int e = blockIdx.x * 256 + threadIdx.x;
  if (e < N_EDGES) atomicAdd(&deg[dst[e]], 1);
}

__global__ __launch_bounds__(256) void dis_kernel(const int* __restrict__ deg,
                                                  float* __restrict__ dis) {
  int n = blockIdx.x * 256 + threadIdx.x;
  if (n < N_NODES) dis[n] = 1.0f / sqrtf((float)deg[n] + 1.0f);
}

__global__ __launch_bounds__(1024) void scan_kernel(const int* __restrict__ deg,
                                                    int* __restrict__ offsets,
                                                    int* __restrict__ cursor) {
  __shared__ int sums[1024];
  int t = threadIdx.x;
  int base = t * 64;
  const int4* dp = (const int4*)(deg + base);
  int s = 0;
#pragma unroll
  for (int i = 0; i < 16; i++) {
    int4 v = dp[i];
    s += v.x + v.y + v.z + v.w;
  }
  sums[t] = s;
  __syncthreads();
  for (int off = 1; off < 1024; off <<= 1) {
    int v = (t >= off) ? sums[t - off] : 0;
    __syncthreads();
    sums[t] += v;
    __syncthreads();
  }
  int run = (t == 0) ? 0 : sums[t - 1];
#pragma unroll
  for (int i = 0; i < 16; i++) {
    int4 v = dp[i];
    int idx = base + i * 4;
    offsets[idx] = run; cursor[idx] = run; run += v.x;
    offsets[idx + 1] = run; cursor[idx + 1] = run; run += v.y;
    offsets[idx + 2] = run; cursor[idx + 2] = run; run += v.z;
    offsets[idx + 3] = run; cursor[idx + 3] = run; run += v.w;
  }
  if (t == 1023) offsets[N_NODES] = run;
}

// fill also precomputes per-edge GCN weight: wedge = dis[src]*dis[dst]
__global__ __launch_bounds__(256) void fill_kernel(const int* __restrict__ src,
                                                   const int* __restrict__ dst,
                                                   const float* __restrict__ dis,
                                                   int* __restrict__ cursor,
                                                   int* __restrict__ csr,
                                                   float* __restrict__ wedge) {
  int e = blockIdx.x * 256 + threadIdx.x;
  if (e < N_EDGES) {
    int d = dst[e];
    int s = src[e];
    int slot = atomicAdd(&cursor[d], 1);
    csr[slot] = s;
    wedge[slot] = dis[s] * dis[d];
  }
}

// ---------------- x -> slab transpose: xs[4][node][16] ----------------
__global__ __launch_bounds__(256) void xslab_kernel(const float* __restrict__ x,
                                                    float* __restrict__ xs) {
  int node = blockIdx.x * 4 + (threadIdx.x >> 6);
  int lane = threadIdx.x & 63;
  int s = lane >> 4, d = lane & 15;
  xs[((size_t)s * N_NODES + node) * 16 + d] = x[(size_t)node * 64 + lane];
}

// ---------------- aggregation over dimension slabs (XCD-L2-resident gathers) ----------
// NS slabs of 16 dims; slab s = blockIdx & (NS-1) -> with round-robin block->XCD
// dispatch, slab s's 4 MB working set pins to one XCD's L2. Wave = 4 edges x 16 dims;
// 4 sequential nodes per wave, 4 waves/block, no LDS/barriers.
template <int NS>
__global__ __launch_bounds__(256) void agg_slab_kernel(
    const float* __restrict__ hs, const float* __restrict__ dis,
    const float* __restrict__ wedge, const int* __restrict__ offsets,
    const int* __restrict__ csr, unsigned short* __restrict__ zhi,
    unsigned short* __restrict__ zlo) {
  int b = blockIdx.x;
  int s = b & (NS - 1);
  int grp = b / NS;
  int w = threadIdx.x >> 6;
  int lane = threadIdx.x & 63;
  int e = lane >> 4, d = lane & 15;
  const float* slab = hs + (size_t)s * N_NODES * 16;
  const int OD = NS * 16;
#pragma unroll 1
  for (int i = 0; i < 4; i++) {
    int node = (grp * 4 + w) * 4 + i;
    int beg = offsets[node], end = offsets[node + 1];
    float acc = 0.0f;
    int k = beg;
    for (; k + 8 <= end; k += 8) {
      int i0 = csr[k + e], i1 = csr[k + 4 + e];
      float w0 = wedge[k + e], w1 = wedge[k + 4 + e];
      float v0 = slab[(size_t)i0 * 16 + d];
      float v1 = slab[(size_t)i1 * 16 + d];
      acc = fmaf(w0, v0, acc);
      acc = fmaf(w1, v1, acc);
    }
    if (k + 4 <= end) {
      int i0 = csr[k + e];
      float w0 = wedge[k + e];
      acc = fmaf(w0, slab[(size_t)i0 * 16 + d], acc);
      k += 4;
    }
    int rem = end - k;
    if (rem > 0) {
      int i0 = (e < rem) ? csr[k + e] : 0;
      float w0 = (e < rem) ? wedge[k + e] : 0.0f;
      acc = fmaf(w0, slab[(size_t)i0 * 16 + d], acc);
    }
    acc += __shfl_xor(acc, 16);
    acc += __shfl_xor(acc, 32);
    if (e == 0) {
      float dn = dis[node];
      float v = fmaf(slab[(size_t)node * 16 + d], dn * dn, acc);
      unsigned short h_, l_;
      split_bf(v, h_, l_);
      zhi[(size_t)node * OD + s * 16 + d] = h_;
      zlo[(size_t)node * OD + s * 16 + d] = l_;
    }
  }
}

// ---------------- weight prep: fp32 W -> bf16 hi/lo in b-fragment layout ----------------
template <bool TRANS>
__global__ __launch_bounds__(256) void wprep_kernel(const float* __restrict__ W, int K, int O,
                                                    unsigned short* __restrict__ hi,
                                                    unsigned short* __restrict__ lo) {
  int idx = blockIdx.x * 256 + threadIdx.x;
  int KC = K / 32;
  int total = (O / 16) * KC * 64;
  if (idx >= total) return;
  int lane = idx & 63;
  int rest = idx >> 6;
  int kc = rest % KC;
  int nt = rest / KC;
  int n = nt * 16 + (lane & 15);
  int kb = kc * 32 + (lane >> 4) * 8;
  unsigned short* hp = hi + (size_t)idx * 8;
  unsigned short* lp = lo + (size_t)idx * 8;
#pragma unroll
  for (int j = 0; j < 8; j++) {
    int k = kb + j;
    float v = TRANS ? W[(size_t)n * K + k] : W[(size_t)k * O + n];
    unsigned short h_, l_;
    split_bf(v, h_, l_);
    hp[j] = h_;
    lp[j] = l_;
  }
}

// ---------------- MFMA GEMM (3 split-products). OUTMODE: 0=f32 row, 1=split bf16,
// 2=f32 slab layout [c>>4][row][c&15] (feeds agg_slab; O must be 128) -----------------
template <int K, int O, bool DOBN, bool DORELU, int OUTMODE>
__global__ __launch_bounds__(256) void gemm_mfma(
    const unsigned short* __restrict__ Ahi, const unsigned short* __restrict__ Alo,
    const unsigned short* __restrict__ Whi, const unsigned short* __restrict__ Wlo,
    const float* __restrict__ bias,
    const float* __restrict__ gamma, const float* __restrict__ beta,
    const float* __restrict__ mean, const float* __restrict__ var,
    float* __restrict__ Cf, unsigned short* __restrict__ Chi,
    unsigned short* __restrict__ Clo) {
  constexpr int KC = K / 32;
  int wave = threadIdx.x >> 6;
  int lane = threadIdx.x & 63;
  int m0 = blockIdx.x * 128 + wave * 32;
  int o0 = blockIdx.y * 128;
  int mrow = lane & 15;
  int kseg = (lane >> 4) * 8;

  f32x4 acc[2][8];
#pragma unroll
  for (int mt = 0; mt < 2; mt++)
#pragma unroll
    for (int nt = 0; nt < 8; nt++) acc[mt][nt] = (f32x4)0.0f;

#pragma unroll
  for (int kc = 0; kc < KC; kc++) {
    bf16x8 ah[2], al[2];
#pragma unroll
    for (int mt = 0; mt < 2; mt++) {
      size_t aoff = (size_t)(m0 + mt * 16 + mrow) * K + kc * 32 + kseg;
      ah[mt] = *(const bf16x8*)(Ahi + aoff);
      al[mt] = *(const bf16x8*)(Alo + aoff);
    }
#pragma unroll
    for (int nt = 0; nt < 8; nt++) {
      size_t foff = (((size_t)(blockIdx.y * 8 + nt) * KC + kc) * 64 + lane) * 8;
      bf16x8 bh = *(const bf16x8*)(Whi + foff);
      bf16x8 bl = *(const bf16x8*)(Wlo + foff);
#pragma unroll
      for (int mt = 0; mt < 2; mt++) {
        acc[mt][nt] = __builtin_amdgcn_mfma_f32_16x16x32_bf16(ah[mt], bh, acc[mt][nt], 0, 0, 0);
        acc[mt][nt] = __builtin_amdgcn_mfma_f32_16x16x32_bf16(ah[mt], bl, acc[mt][nt], 0, 0, 0);
        acc[mt][nt] = __builtin_amdgcn_mfma_f32_16x16x32_bf16(al[mt], bh, acc[mt][nt], 0, 0, 0);
      }
    }
  }

  int ccol = lane & 15;
  int crow0 = (lane >> 4) * 4;
#pragma unroll
  for (int nt = 0; nt < 8; nt++) {
    int c = o0 + nt * 16 + ccol;
    float sc, cb;
    float b = bias[c];
    if (DOBN) {
      sc = gamma[c] * rsqrtf(var[c] + BN_EPS);
      cb = (b - mean[c]) * sc + beta[c];
    } else {
      sc = 1.0f;
      cb = b;
    }
#pragma unroll
    for (int mt = 0; mt < 2; mt++) {
#pragma unroll
      for (int r = 0; r < 4; r++) {
        float v = fmaf(acc[mt][nt][r], sc, cb);
        if (DORELU) v = fmaxf(v, 0.0f);
        size_t row = (size_t)(m0 + mt * 16 + crow0 + r);
        if (OUTMODE == 1) {
          unsigned short h_, l_;
          split_bf(v, h_, l_);
          Chi[row * O + c] = h_;
          Clo[row * O + c] = l_;
        } else if (OUTMODE == 2) {
          Cf[((size_t)(c >> 4) * N_NODES + row) * 16 + (c & 15)] = v;
        } else {
          Cf[row * O + c] = v;
        }
      }
    }
  }
}

// ---------------- key-norm max per (graph, head) ----------------
__global__ __launch_bounds__(256) void knorm_kernel(const float* __restrict__ qkv,
                                                    float* __restrict__ kmax2) {
  int g = blockIdx.x >> 2;
  int h = blockIdx.x & 3;
  size_t gbase = (size_t)g * NPG;
  float best = 0.0f;
#pragma unroll
  for (int r = 0; r < 2; r++) {
    int j = r * 256 + threadIdx.x;
    const float* kp = &qkv[(gbase + j) * 384 + 128 + h * 32];
    float s = 0.0f;
#pragma unroll
    for (int i = 0; i < 8; i++) {
      float4 v = *(const float4*)(kp + i * 4);
      s = fmaf(v.x, v.x, s);
      s = fmaf(v.y, v.y, s);
      s = fmaf(v.z, v.z, s);
      s = fmaf(v.w, v.w, s);
    }
    best = fmaxf(best, s);
  }
#pragma unroll
  for (int off = 32; off >= 1; off >>= 1)
    best = fmaxf(best, __shfl_xor(best, off, 64));
  __shared__ float red[4];
  int wave = threadIdx.x >> 6;
  if ((threadIdx.x & 63) == 0) red[wave] = best;
  __syncthreads();
  if (threadIdx.x == 0) {
    float m = fmaxf(fmaxf(red[0], red[1]), fmaxf(red[2], red[3]));
    kmax2[blockIdx.x] = m;
  }
}

// ---------------- attention via MFMA (R8 version, kept) ----------------
__global__ __launch_bounds__(256, 2) void attn_mfma_kernel(
    const float* __restrict__ qkv, const float* __restrict__ kmax2,
    unsigned short* __restrict__ ohi, unsigned short* __restrict__ olo) {
  int b = blockIdx.x;
  int g = b >> 3;
  int h = (b >> 1) & 3;
  int half = b & 1;
  int t = threadIdx.x;
  int wave = t >> 6;
  int lane = t & 63;
  int quad = lane >> 4;
  int l15 = lane & 15;
  size_t gbase = (size_t)g * NPG;
  int qb = half * 256 + wave * 64;

  const float cf = 0.17677669529663687f * 1.4426950408889634f;  // scale*log2(e)

  __shared__ unsigned short Kh[32][36], Kl[32][36];
  __shared__ unsigned short Vh[33][36], Vl[33][36];
  __shared__ char wbuf[4][9472] __attribute__((aligned(16)));

  unsigned short* Ph = (unsigned short*)wbuf[wave];
  unsigned short* Pl = Ph + 64 * 36;
  float* Ot = (float*)wbuf[wave];

  bf16x8 qh[4], ql[4];
  float qn2p[4];
#pragma unroll
  for (int mt = 0; mt < 4; mt++) {
    const float* qp = &qkv[(gbase + qb + mt * 16 + l15) * 384 + h * 32 + quad * 8];
    float4 f0 = *(const float4*)qp;
    float4 f1 = *(const float4*)(qp + 4);
    float v[8] = {f0.x * cf, f0.y * cf, f0.z * cf, f0.w * cf,
                  f1.x * cf, f1.y * cf, f1.z * cf, f1.w * cf};
    u16x8 hh, ll;
    float s = 0.0f;
#pragma unroll
    for (int j = 0; j < 8; j++) {
      unsigned short hi_, lo_;
      split_bf(v[j], hi_, lo_);
      hh[j] = hi_;
      ll[j] = lo_;
      s = fmaf(v[j], v[j], s);
    }
    qh[mt] = __builtin_bit_cast(bf16x8, hh);
    ql[mt] = __builtin_bit_cast(bf16x8, ll);
    s += __shfl_xor(s, 16);
    s += __shfl_xor(s, 32);
    qn2p[mt] = s;
  }
  if (quad == 0) {
#pragma unroll
    for (int mt = 0; mt < 4; mt++) Ot[mt * 16 + l15] = qn2p[mt];
  }
  float km2 = kmax2[g * 4 + h];
  float Mq[4][4];
#pragma unroll
  for (int mt = 0; mt < 4; mt++)
#pragma unroll
    for (int r = 0; r < 4; r++)
      Mq[mt][r] = sqrtf(Ot[mt * 16 + quad * 4 + r] * km2);

  f32x4 Oa[4][3];
#pragma unroll
  for (int mt = 0; mt < 4; mt++)
#pragma unroll
    for (int nt = 0; nt < 3; nt++) Oa[mt][nt] = (f32x4)0.0f;

  for (int c = 0; c < 16; c++) {
    __syncthreads();
    if (t >= 128) {
      int t2 = t - 128;
      int key = t2 >> 2;
      int ds = (t2 & 3) * 8;
      const float* kp = &qkv[(gbase + (size_t)(c * 32 + key)) * 384 + 128 + h * 32 + ds];
      float4 f0 = *(const float4*)kp;
      float4 f1 = *(const float4*)(kp + 4);
      float v[8] = {f0.x, f0.y, f0.z, f0.w, f1.x, f1.y, f1.z, f1.w};
      u16x4 h0, h1, l0, l1;
#pragma unroll
      for (int j = 0; j < 4; j++) {
        unsigned short hi_, lo_;
        split_bf(v[j], hi_, lo_);
        h0[j] = hi_; l0[j] = lo_;
        split_bf(v[j + 4], hi_, lo_);
        h1[j] = hi_; l1[j] = lo_;
      }
      *(u16x4*)&Kh[key][ds] = h0;
      *(u16x4*)&Kh[key][ds + 4] = h1;
      *(u16x4*)&Kl[key][ds] = l0;
      *(u16x4*)&Kl[key][ds + 4] = l1;
    } else if (t < 64) {
      int keyb = (t & 7) * 4;
      int dvb = (t >> 3) * 4;
      float4 r0 = *(const float4*)&qkv[(gbase + (size_t)(c * 32 + keyb + 0)) * 384 + 256 + h * 32 + dvb];
      float4 r1 = *(const float4*)&qkv[(gbase + (size_t)(c * 32 + keyb + 1)) * 384 + 256 + h * 32 + dvb];
      float4 r2 = *(const float4*)&qkv[(gbase + (size_t)(c * 32 + keyb + 2)) * 384 + 256 + h * 32 + dvb];
      float4 r3 = *(const float4*)&qkv[(gbase + (size_t)(c * 32 + keyb + 3)) * 384 + 256 + h * 32 + dvb];
      float rr[4][4] = {{r0.x, r0.y, r0.z, r0.w}, {r1.x, r1.y, r1.z, r1.w},
                        {r2.x, r2.y, r2.z, r2.w}, {r3.x, r3.y, r3.z, r3.w}};
#pragma unroll
      for (int c2 = 0; c2 < 4; c2++) {
        ushort4 hv, lv;
        unsigned short hi_, lo_;
        split_bf(rr[0][c2], hi_, lo_); hv.x = hi_; lv.x = lo_;
        split_bf(rr[1][c2], hi_, lo_); hv.y = hi_; lv.y = lo_;
        split_bf(rr[2][c2], hi_, lo_); hv.z = hi_; lv.z = lo_;
        split_bf(rr[3][c2], hi_, lo_); hv.w = hi_; lv.w = lo_;
        *(ushort4*)&Vh[dvb + c2][keyb] = hv;
        *(ushort4*)&Vl[dvb + c2][keyb] = lv;
      }
    } else if (t < 68) {
      int i = t - 64;
      u16x8 ones;
#pragma unroll
      for (int j = 0; j < 8; j++) ones[j] = 0x3F80;
      *(u16x4*)&Vh[32][i * 8] = __builtin_shufflevector(ones, ones, 0, 1, 2, 3);
      *(u16x4*)&Vh[32][i * 8 + 4] = __builtin_shufflevector(ones, ones, 4, 5, 6, 7);
    }
    __syncthreads();

#pragma unroll
    for (int nt = 0; nt < 2; nt++) {
      bf16x8 bkh = ld_bf8(&Kh[nt * 16 + l15][quad * 8]);
      bf16x8 bkl = ld_bf8(&Kl[nt * 16 + l15][quad * 8]);
#pragma unroll
      for (int mt = 0; mt < 4; mt++) {
        f32x4 S = (f32x4)0.0f;
        S = __builtin_amdgcn_mfma_f32_16x16x32_bf16(qh[mt], bkh, S, 0, 0, 0);
        S = __builtin_amdgcn_mfma_f32_16x16x32_bf16(qh[mt], bkl, S, 0, 0, 0);
        S = __builtin_amdgcn_mfma_f32_16x16x32_bf16(ql[mt], bkh, S, 0, 0, 0);
#pragma unroll
        for (int r = 0; r < 4; r++) {
          float p = __builtin_exp2f(S[r] - Mq[mt][r]);
          unsigned short hi_, lo_;
          split_bf(p, hi_, lo_);
          int row = mt * 16 + quad * 4 + r;
          Ph[row * 36 + nt * 16 + l15] = hi_;
          Pl[row * 36 + nt * 16 + l15] = lo_;
        }
      }
    }
    bf16x8 pah[4], pal[4];
#pragma unroll
    for (int mt = 0; mt < 4; mt++) {
      pah[mt] = ld_bf8(&Ph[(mt * 16 + l15) * 36 + quad * 8]);
      pal[mt] = ld_bf8(&Pl[(mt * 16 + l15) * 36 + quad * 8]);
    }
#pragma unroll
    for (int nt = 0; nt < 3; nt++) {
      bf16x8 bvh = ld_bf8(&Vh[nt * 16 + l15][quad * 8]);
      if (nt < 2) {
        bf16x8 bvl = ld_bf8(&Vl[nt * 16 + l15][quad * 8]);
#pragma unroll
        for (int mt = 0; mt < 4; mt++) {
          Oa[mt][nt] = __builtin_amdgcn_mfma_f32_16x16x32_bf16(pah[mt], bvh, Oa[mt][nt], 0, 0, 0);
          Oa[mt][nt] = __builtin_amdgcn_mfma_f32_16x16x32_bf16(pah[mt], bvl, Oa[mt][nt], 0, 0, 0);
          Oa[mt][nt] = __builtin_amdgcn_mfma_f32_16x16x32_bf16(pal[mt], bvh, Oa[mt][nt], 0, 0, 0);
        }
      } else {
#pragma unroll
        for (int mt = 0; mt < 4; mt++) {
          Oa[mt][nt] = __builtin_amdgcn_mfma_f32_16x16x32_bf16(pah[mt], bvh, Oa[mt][nt], 0, 0, 0);
          Oa[mt][nt] = __builtin_amdgcn_mfma_f32_16x16x32_bf16(pal[mt], bvh, Oa[mt][nt], 0, 0, 0);
        }
      }
    }
  }

#pragma unroll
  for (int mt = 0; mt < 4; mt++) {
#pragma unroll
    for (int r = 0; r < 4; r++) {
      int row = mt * 16 + quad * 4 + r;
      Ot[row * 37 + l15] = Oa[mt][0][r];
      Ot[row * 37 + 16 + l15] = Oa[mt][1][r];
      if (l15 == 0) Ot[row * 37 + 32] = Oa[mt][2][r];
    }
  }
  {
    int row = lane;
    float inv = 1.0f / Ot[row * 37 + 32];
    size_t node = gbase + qb + row;
    u16x8 vh, vl;
#pragma unroll
    for (int seg = 0; seg < 4; seg++) {
#pragma unroll
      for (int j = 0; j < 8; j++) {
        unsigned short hi_, lo_;
        split_bf(Ot[row * 37 + seg * 8 + j] * inv, hi_, lo_);
        vh[j] = hi_;
        vl[j] = lo_;
      }
      *(u16x8*)(ohi + node * 128 + h * 32 + seg * 8) = vh;
      *(u16x8*)(olo + node * 128 + h * 32 + seg * 8) = vl;
    }
  }
}

// ---------------- mean pool ----------------
__global__ __launch_bounds__(128) void pool_kernel(const float* __restrict__ fin,
                                                   float* __restrict__ emb) {
  int g = blockIdx.x, c = threadIdx.x;
  const float* p = fin + (size_t)g * NPG * HID + c;
  float s = 0.0f;
  for (int i = 0; i < NPG; i++) s += p[(size_t)i * HID];
  emb[g * HID + c] = s * (1.0f / NPG);
}

extern "C" void kernel_launch(void* const* d_in, const int* in_sizes, int n_in,
                              void* d_out, int out_size, void* d_ws, size_t ws_size,
                              hipStream_t stream) {
  (void)in_sizes; (void)n_in; (void)out_size; (void)ws_size;
  const float* x          = (const float*)d_in[0];
  const float* W0         = (const float*)d_in[1];
  const float* b0         = (const float*)d_in[2];
  const float* Wh         = (const float*)d_in[3];
  const float* bh         = (const float*)d_in[4];
  const float* bn_gamma   = (const float*)d_in[5];
  const float* bn_beta    = (const float*)d_in[6];
  const float* bn_mean    = (const float*)d_in[7];
  const float* bn_var     = (const float*)d_in[8];
  const float* attn_in_w  = (const float*)d_in[9];
  const float* attn_in_b  = (const float*)d_in[10];
  const float* attn_out_w = (const float*)d_in[11];
  const float* attn_out_b = (const float*)d_in[12];
  const int* edge_index   = (const int*)d_in[13];
  const int* src = edge_index;
  const int* dst = edge_index + N_EDGES;

  char* ws = (char*)d_ws;
  size_t off = 0;
  auto alloc = [&](size_t bytes) -> void* {
    void* p = ws + off;
    off += (bytes + 255) & ~(size_t)255;
    return p;
  };
  int*   deg     = (int*)alloc((size_t)N_NODES * 4);
  int*   offsets = (int*)alloc((size_t)(N_NODES + 1) * 4);
  int*   cursor  = (int*)alloc((size_t)N_NODES * 4);
  int*   csr     = (int*)alloc((size_t)N_EDGES * 4);
  float* wedge   = (float*)alloc((size_t)N_EDGES * 4);
  float* dis     = (float*)alloc((size_t)N_NODES * 4);
  float* hsl     = (float*)alloc((size_t)N_NODES * HID * 4);   // 8 slabs; later f_hi/f_lo
  float* xs      = (float*)alloc((size_t)N_NODES * 64 * 4);    // 4 slabs of x
  unsigned short* zhi = (unsigned short*)alloc((size_t)N_NODES * HID * 2);  // also o_hi
  unsigned short* zlo = (unsigned short*)alloc((size_t)N_NODES * HID * 2);  // also o_lo
  float* qkvb    = (float*)alloc((size_t)N_NODES * 384 * 4);
  float* kmax2   = (float*)alloc((size_t)N_GRAPHS * 4 * 4);
  unsigned short* w0h = (unsigned short*)alloc(8192 * 2);
  unsigned short* w0l = (unsigned short*)alloc(8192 * 2);
  unsigned short* whh[3], *whl[3];
  for (int i = 0; i < 3; i++) {
    whh[i] = (unsigned short*)alloc(16384 * 2);
    whl[i] = (unsigned short*)alloc(16384 * 2);
  }
  unsigned short* wqh = (unsigned short*)alloc(49152 * 2);
  unsigned short* wql = (unsigned short*)alloc(49152 * 2);
  unsigned short* woh = (unsigned short*)alloc(16384 * 2);
  unsigned short* wol = (unsigned short*)alloc(16384 * 2);

  unsigned short* fhi = (unsigned short*)hsl;   // reuse hsl region for f split
  unsigned short* flo = fhi + (size_t)N_NODES * HID;

  float* fin = (float*)d_out;                       // [N, HID]
  float* emb = fin + (size_t)N_NODES * HID;         // [G, HID]

  hipMemsetAsync(deg, 0, (size_t)N_NODES * 4, stream);
  hist_kernel<<<N_EDGES / 256, 256, 0, stream>>>(dst, deg);
  dis_kernel<<<N_NODES / 256, 256, 0, stream>>>(deg, dis);
  scan_kernel<<<1, 1024, 0, stream>>>(deg, offsets, cursor);
  fill_kernel<<<N_EDGES / 256, 256, 0, stream>>>(src, dst, dis, cursor, csr, wedge);

  wprep_kernel<false><<<4, 256, 0, stream>>>(W0, 64, 128, w0h, w0l);
  for (int i = 0; i < 3; i++)
    wprep_kernel<false><<<8, 256, 0, stream>>>(Wh + (size_t)i * HID * HID, 128, 128,
                                               whh[i], whl[i]);
  wprep_kernel<true><<<24, 256, 0, stream>>>(attn_in_w, 128, 384, wqh, wql);
  wprep_kernel<true><<<8, 256, 0, stream>>>(attn_out_w, 128, 128, woh, wol);

  xslab_kernel<<<N_NODES / 4, 256, 0, stream>>>(x, xs);

  dim3 ggrid(N_NODES / 128, 1);
  // layer 0: 4-slab aggregation of x, GEMM -> 8-slab h
  agg_slab_kernel<4><<<(N_NODES / 16) * 4, 256, 0, stream>>>(
      xs, dis, wedge, offsets, csr, zhi, zlo);
  gemm_mfma<64, 128, true, true, 2><<<ggrid, 256, 0, stream>>>(
      zhi, zlo, w0h, w0l, b0, bn_gamma, bn_beta, bn_mean, bn_var, hsl, nullptr, nullptr);
  // layers 1,2: 8-slab agg + GEMM -> 8-slab h
  for (int L = 0; L < 2; L++) {
    agg_slab_kernel<8><<<(N_NODES / 16) * 8, 256, 0, stream>>>(
        hsl, dis, wedge, offsets, csr, zhi, zlo);
    gemm_mfma<128, 128, true, true, 2><<<ggrid, 256, 0, stream>>>(
        zhi, zlo, whh[L], whl[L], bh + (size_t)L * HID,
        bn_gamma + (size_t)(L + 1) * HID, bn_beta + (size_t)(L + 1) * HID,
        bn_mean + (size_t)(L + 1) * HID, bn_var + (size_t)(L + 1) * HID,
        hsl, nullptr, nullptr);
  }
  // layer 3: agg reads hsl; GEMM writes f split into hsl region (no overlap hazard:
  // gemm reads only zhi/zlo)
  agg_slab_kernel<8><<<(N_NODES / 16) * 8, 256, 0, stream>>>(
      hsl, dis, wedge, offsets, csr, zhi, zlo);
  gemm_mfma<128, 128, true, true, 1><<<ggrid, 256, 0, stream>>>(
      zhi, zlo, whh[2], whl[2], bh + (size_t)2 * HID,
      bn_gamma + (size_t)3 * HID, bn_beta + (size_t)3 * HID,
      bn_mean + (size_t)3 * HID, bn_var + (size_t)3 * HID,
      nullptr, fhi, flo);
  dim3 qgrid(N_NODES / 128, 3);
  gemm_mfma<128, 384, false, false, 0><<<qgrid, 256, 0, stream>>>(
      fhi, flo, wqh, wql, attn_in_b, nullptr, nullptr, nullptr, nullptr,
      qkvb, nullptr, nullptr);
  knorm_kernel<<<N_GRAPHS * 4, 256, 0, stream>>>(qkvb, kmax2);
  attn_mfma_kernel<<<N_GRAPHS * 4 * 2, 256, 0, stream>>>(qkvb, kmax2, zhi, zlo);
  gemm_mfma<128, 128, false, false, 0><<<ggrid, 256, 0, stream>>>(
      zhi, zlo, woh, wol, attn_out_b, nullptr, nullptr, nullptr, nullptr,
      fin, nullptr, nullptr);
  pool_kernel<<<N_GRAPHS, 128, 0, stream>>>(fin, emb);
}

// Round 11
// 1007.764 us; speedup vs baseline: 1.2207x; 1.2207x over previous
//
#include <hip/hip_runtime.h>
#include <hip/hip_bf16.h>
#include <cstdint>
#include <cstddef>

#define N_NODES 65536
#define N_EDGES 1048576
#define N_GRAPHS 128
#define NPG 512
#define IN_DIM 64
#define HID 128
#define BN_EPS 1e-5f

typedef __attribute__((ext_vector_type(8))) short bf16x8;
typedef __attribute__((ext_vector_type(4))) float f32x4;
typedef __attribute__((ext_vector_type(8))) unsigned short u16x8;
typedef __attribute__((ext_vector_type(4))) unsigned short u16x4;

// ---- bf16 helpers (RNE, matches v_cvt) ----
__device__ inline unsigned short f2bf(float f) {
  unsigned u = __builtin_bit_cast(unsigned, f);
  u = u + 0x7fffu + ((u >> 16) & 1u);
  return (unsigned short)(u >> 16);
}
__device__ inline float bf2f(unsigned short h) {
  unsigned u = ((unsigned)h) << 16;
  return __builtin_bit_cast(float, u);
}
__device__ inline void split_bf(float v, unsigned short& hi, unsigned short& lo) {
  hi = f2bf(v);
  lo = f2bf(v - bf2f(hi));
}
// 8-B-aligned LDS fragment load (two ds_read_b64)
__device__ inline bf16x8 ld_bf8(const unsigned short* p) {
  u16x4 a = *(const u16x4*)p;
  u16x4 b = *(const u16x4*)(p + 4);
  u16x8 r = __builtin_shufflevector(a, b, 0, 1, 2, 3, 4, 5, 6, 7);
  return __builtin_bit_cast(bf16x8, r);
}

// ---------------- CSR build ----------------
__global__ __launch_bounds__(256) void hist_kernel(const int* __restrict__ dst,
                                                   int* __restrict__ deg) {
  int e = blockIdx.x * 256 + threadIdx.x;
  if (e < N_EDGES) atomicAdd(&deg[dst[e]], 1);
}

__global__ __launch_bounds__(256) void dis_kernel(const int* __restrict__ deg,
                                                  float* __restrict__ dis) {
  int n = blockIdx.x * 256 + threadIdx.x;
  if (n < N_NODES) dis[n] = 1.0f / sqrtf((float)deg[n] + 1.0f);
}

__global__ __launch_bounds__(1024) void scan_kernel(const int* __restrict__ deg,
                                                    int* __restrict__ offsets,
                                                    int* __restrict__ cursor) {
  __shared__ int sums[1024];
  int t = threadIdx.x;
  int base = t * 64;
  const int4* dp = (const int4*)(deg + base);
  int s = 0;
#pragma unroll
  for (int i = 0; i < 16; i++) {
    int4 v = dp[i];
    s += v.x + v.y + v.z + v.w;
  }
  sums[t] = s;
  __syncthreads();
  for (int off = 1; off < 1024; off <<= 1) {
    int v = (t >= off) ? sums[t - off] : 0;
    __syncthreads();
    sums[t] += v;
    __syncthreads();
  }
  int run = (t == 0) ? 0 : sums[t - 1];
#pragma unroll
  for (int i = 0; i < 16; i++) {
    int4 v = dp[i];
    int idx = base + i * 4;
    offsets[idx] = run; cursor[idx] = run; run += v.x;
    offsets[idx + 1] = run; cursor[idx + 1] = run; run += v.y;
    offsets[idx + 2] = run; cursor[idx + 2] = run; run += v.z;
    offsets[idx + 3] = run; cursor[idx + 3] = run; run += v.w;
  }
  if (t == 1023) offsets[N_NODES] = run;
}

// fill also precomputes per-edge GCN weight: wedge = dis[src]*dis[dst]
__global__ __launch_bounds__(256) void fill_kernel(const int* __restrict__ src,
                                                   const int* __restrict__ dst,
                                                   const float* __restrict__ dis,
                                                   int* __restrict__ cursor,
                                                   int* __restrict__ csr,
                                                   float* __restrict__ wedge) {
  int e = blockIdx.x * 256 + threadIdx.x;
  if (e < N_EDGES) {
    int d = dst[e];
    int s = src[e];
    int slot = atomicAdd(&cursor[d], 1);
    csr[slot] = s;
    wedge[slot] = dis[s] * dis[d];
  }
}

// ---------------- weight prep: fp32 W -> bf16 hi/lo in b-fragment layout ----------------
template <bool TRANS>
__global__ __launch_bounds__(256) void wprep_kernel(const float* __restrict__ W, int K, int O,
                                                    unsigned short* __restrict__ hi,
                                                    unsigned short* __restrict__ lo) {
  int idx = blockIdx.x * 256 + threadIdx.x;
  int KC = K / 32;
  int total = (O / 16) * KC * 64;
  if (idx >= total) return;
  int lane = idx & 63;
  int rest = idx >> 6;
  int kc = rest % KC;
  int nt = rest / KC;
  int n = nt * 16 + (lane & 15);
  int kb = kc * 32 + (lane >> 4) * 8;
  unsigned short* hp = hi + (size_t)idx * 8;
  unsigned short* lp = lo + (size_t)idx * 8;
#pragma unroll
  for (int j = 0; j < 8; j++) {
    int k = kb + j;
    float v = TRANS ? W[(size_t)n * K + k] : W[(size_t)k * O + n];
    unsigned short h_, l_;
    split_bf(v, h_, l_);
    hp[j] = h_;
    lp[j] = l_;
  }
}

// ---------------- fused aggregation + MFMA GEMM ----------------
// One block = 128 nodes (rows). Phase A: wave w aggregates its 32 contiguous nodes
// (R9 gather loop) and writes split-bf16 z into wave-local LDS with an XOR dim-group
// swizzle (keeps stride K conflict-free: writes 2-way, frag reads 2-way — free).
// Phase B: MFMA GEMM with A-frags from LDS, B-frags (weights) from global.
// OUTMODE: 0 = fp32 [N,128] rows; 1 = split-bf16 hi/lo.
template <int K, int OUTMODE>
__global__ __launch_bounds__(256, 2) void fused_agg_gemm(
    const float* __restrict__ h, const float* __restrict__ dis,
    const float* __restrict__ wedge, const int* __restrict__ offsets,
    const int* __restrict__ csr,
    const unsigned short* __restrict__ Whi, const unsigned short* __restrict__ Wlo,
    const float* __restrict__ bias,
    const float* __restrict__ gamma, const float* __restrict__ beta,
    const float* __restrict__ mean, const float* __restrict__ var,
    float* __restrict__ Cf, unsigned short* __restrict__ Chi,
    unsigned short* __restrict__ Clo) {
  constexpr int KC = K / 32;
  constexpr int O = 128;
  int wave = threadIdx.x >> 6;
  int lane = threadIdx.x & 63;
  int quad = lane >> 4;
  int l15 = lane & 15;
  int m0 = blockIdx.x * 128;
  int base = m0 + wave * 32;

  __shared__ unsigned short Zh[4][32][K], Zl[4][32][K];

  // ---- phase A: aggregate 32 nodes (wave-per-node rows of this wave's tile) ----
  int go = lane & 7;
  int gl = lane >> 3;  // dim group 0..7
  for (int r = 0; r < 32; r++) {
    int node = base + r;
    float dn = dis[node];
    float sn = dn * dn;
    int beg = offsets[node], end = offsets[node + 1];
    float a0, a1 = 0.0f;
    if (K == 64) {
      a0 = h[(size_t)node * 64 + lane] * sn;
    } else {
      const float* hr = h + (size_t)node * 128;
      a0 = hr[lane] * sn;
      a1 = hr[lane + 64] * sn;
    }
    int k = beg;
    for (; k + 8 <= end; k += 8) {
      int s[8];
      float w[8], u[8], d[8];
#pragma unroll
      for (int i = 0; i < 8; i++) {
        s[i] = csr[k + i];
        w[i] = wedge[k + i];
      }
      if (K == 64) {
#pragma unroll
        for (int i = 0; i < 8; i++) u[i] = h[(size_t)s[i] * 64 + lane];
#pragma unroll
        for (int i = 0; i < 8; i++) a0 = fmaf(w[i], u[i], a0);
      } else {
#pragma unroll
        for (int i = 0; i < 8; i++) {
          const float* p = h + (size_t)s[i] * 128;
          u[i] = p[lane];
          d[i] = p[lane + 64];
        }
#pragma unroll
        for (int i = 0; i < 8; i++) {
          a0 = fmaf(w[i], u[i], a0);
          a1 = fmaf(w[i], d[i], a1);
        }
      }
    }
    for (; k < end; k++) {
      int s = csr[k];
      float wt = wedge[k];
      if (K == 64) {
        a0 = fmaf(wt, h[(size_t)s * 64 + lane], a0);
      } else {
        const float* hs = h + (size_t)s * 128;
        a0 = fmaf(wt, hs[lane], a0);
        a1 = fmaf(wt, hs[lane + 64], a1);
      }
    }
    int rx = r & 7;
    int gs = (gl ^ rx) & 7;
    unsigned short h0, l0;
    split_bf(a0, h0, l0);
    int d0 = (gs << 3) | go;
    Zh[wave][r][d0] = h0;
    Zl[wave][r][d0] = l0;
    if (K == 128) {
      unsigned short h1, l1;
      split_bf(a1, h1, l1);
      int d1 = ((8 | gs) << 3) | go;
      Zh[wave][r][d1] = h1;
      Zl[wave][r][d1] = l1;
    }
  }
  __syncthreads();

  // ---- phase B: GEMM, A-frags from LDS (swizzled), B-frags from global ----
  f32x4 acc[2][8];
#pragma unroll
  for (int mt = 0; mt < 2; mt++)
#pragma unroll
    for (int nt = 0; nt < 8; nt++) acc[mt][nt] = (f32x4)0.0f;

#pragma unroll
  for (int kc = 0; kc < KC; kc++) {
    bf16x8 ah[2], al[2];
#pragma unroll
    for (int mt = 0; mt < 2; mt++) {
      int r = mt * 16 + l15;
      int rx = r & 7;
      int g = kc * 4 + quad;
      int gp = (g & 8) | ((g ^ rx) & 7);
      ah[mt] = ld_bf8(&Zh[wave][r][gp * 8]);
      al[mt] = ld_bf8(&Zl[wave][r][gp * 8]);
    }
#pragma unroll
    for (int nt = 0; nt < 8; nt++) {
      size_t foff = (((size_t)nt * KC + kc) * 64 + lane) * 8;
      bf16x8 bh = *(const bf16x8*)(Whi + foff);
      bf16x8 bl = *(const bf16x8*)(Wlo + foff);
#pragma unroll
      for (int mt = 0; mt < 2; mt++) {
        acc[mt][nt] = __builtin_amdgcn_mfma_f32_16x16x32_bf16(ah[mt], bh, acc[mt][nt], 0, 0, 0);
        acc[mt][nt] = __builtin_amdgcn_mfma_f32_16x16x32_bf16(ah[mt], bl, acc[mt][nt], 0, 0, 0);
        acc[mt][nt] = __builtin_amdgcn_mfma_f32_16x16x32_bf16(al[mt], bh, acc[mt][nt], 0, 0, 0);
      }
    }
  }

  int ccol = l15;
  int crow0 = quad * 4;
#pragma unroll
  for (int nt = 0; nt < 8; nt++) {
    int c = nt * 16 + ccol;
    float b = bias[c];
    float sc = gamma[c] * rsqrtf(var[c] + BN_EPS);
    float cb = (b - mean[c]) * sc + beta[c];
#pragma unroll
    for (int mt = 0; mt < 2; mt++) {
#pragma unroll
      for (int r = 0; r < 4; r++) {
        float v = fmaf(acc[mt][nt][r], sc, cb);
        v = fmaxf(v, 0.0f);
        size_t row = (size_t)(m0 + wave * 32 + mt * 16 + crow0 + r);
        if (OUTMODE == 1) {
          unsigned short h_, l_;
          split_bf(v, h_, l_);
          Chi[row * O + c] = h_;
          Clo[row * O + c] = l_;
        } else {
          Cf[row * O + c] = v;
        }
      }
    }
  }
}

// ---------------- MFMA GEMM (standalone: qkv and output projection) ----------------
template <int K, int O, bool DOBN, bool DORELU, int OUTMODE>
__global__ __launch_bounds__(256) void gemm_mfma(
    const unsigned short* __restrict__ Ahi, const unsigned short* __restrict__ Alo,
    const unsigned short* __restrict__ Whi, const unsigned short* __restrict__ Wlo,
    const float* __restrict__ bias,
    const float* __restrict__ gamma, const float* __restrict__ beta,
    const float* __restrict__ mean, const float* __restrict__ var,
    float* __restrict__ Cf, unsigned short* __restrict__ Chi,
    unsigned short* __restrict__ Clo) {
  constexpr int KC = K / 32;
  int wave = threadIdx.x >> 6;
  int lane = threadIdx.x & 63;
  int m0 = blockIdx.x * 128 + wave * 32;
  int o0 = blockIdx.y * 128;
  int mrow = lane & 15;
  int kseg = (lane >> 4) * 8;

  f32x4 acc[2][8];
#pragma unroll
  for (int mt = 0; mt < 2; mt++)
#pragma unroll
    for (int nt = 0; nt < 8; nt++) acc[mt][nt] = (f32x4)0.0f;

#pragma unroll
  for (int kc = 0; kc < KC; kc++) {
    bf16x8 ah[2], al[2];
#pragma unroll
    for (int mt = 0; mt < 2; mt++) {
      size_t aoff = (size_t)(m0 + mt * 16 + mrow) * K + kc * 32 + kseg;
      ah[mt] = *(const bf16x8*)(Ahi + aoff);
      al[mt] = *(const bf16x8*)(Alo + aoff);
    }
#pragma unroll
    for (int nt = 0; nt < 8; nt++) {
      size_t foff = (((size_t)(blockIdx.y * 8 + nt) * KC + kc) * 64 + lane) * 8;
      bf16x8 bh = *(const bf16x8*)(Whi + foff);
      bf16x8 bl = *(const bf16x8*)(Wlo + foff);
#pragma unroll
      for (int mt = 0; mt < 2; mt++) {
        acc[mt][nt] = __builtin_amdgcn_mfma_f32_16x16x32_bf16(ah[mt], bh, acc[mt][nt], 0, 0, 0);
        acc[mt][nt] = __builtin_amdgcn_mfma_f32_16x16x32_bf16(ah[mt], bl, acc[mt][nt], 0, 0, 0);
        acc[mt][nt] = __builtin_amdgcn_mfma_f32_16x16x32_bf16(al[mt], bh, acc[mt][nt], 0, 0, 0);
      }
    }
  }

  int ccol = lane & 15;
  int crow0 = (lane >> 4) * 4;
#pragma unroll
  for (int nt = 0; nt < 8; nt++) {
    int c = o0 + nt * 16 + ccol;
    float sc, cb;
    float b = bias[c];
    if (DOBN) {
      sc = gamma[c] * rsqrtf(var[c] + BN_EPS);
      cb = (b - mean[c]) * sc + beta[c];
    } else {
      sc = 1.0f;
      cb = b;
    }
#pragma unroll
    for (int mt = 0; mt < 2; mt++) {
#pragma unroll
      for (int r = 0; r < 4; r++) {
        float v = fmaf(acc[mt][nt][r], sc, cb);
        if (DORELU) v = fmaxf(v, 0.0f);
        size_t row = (size_t)(m0 + mt * 16 + crow0 + r);
        if (OUTMODE == 1) {
          unsigned short h_, l_;
          split_bf(v, h_, l_);
          Chi[row * O + c] = h_;
          Clo[row * O + c] = l_;
        } else {
          Cf[row * O + c] = v;
        }
      }
    }
  }
}

// ---------------- key-norm max per (graph, head) ----------------
__global__ __launch_bounds__(256) void knorm_kernel(const float* __restrict__ qkv,
                                                    float* __restrict__ kmax2) {
  int g = blockIdx.x >> 2;
  int h = blockIdx.x & 3;
  size_t gbase = (size_t)g * NPG;
  float best = 0.0f;
#pragma unroll
  for (int r = 0; r < 2; r++) {
    int j = r * 256 + threadIdx.x;
    const float* kp = &qkv[(gbase + j) * 384 + 128 + h * 32];
    float s = 0.0f;
#pragma unroll
    for (int i = 0; i < 8; i++) {
      float4 v = *(const float4*)(kp + i * 4);
      s = fmaf(v.x, v.x, s);
      s = fmaf(v.y, v.y, s);
      s = fmaf(v.z, v.z, s);
      s = fmaf(v.w, v.w, s);
    }
    best = fmaxf(best, s);
  }
#pragma unroll
  for (int off = 32; off >= 1; off >>= 1)
    best = fmaxf(best, __shfl_xor(best, off, 64));
  __shared__ float red[4];
  int wave = threadIdx.x >> 6;
  if ((threadIdx.x & 63) == 0) red[wave] = best;
  __syncthreads();
  if (threadIdx.x == 0) {
    float m = fmaxf(fmaxf(red[0], red[1]), fmaxf(red[2], red[3]));
    kmax2[blockIdx.x] = m;
  }
}

// ---------------- attention via MFMA (R8 version, kept) ----------------
__global__ __launch_bounds__(256, 2) void attn_mfma_kernel(
    const float* __restrict__ qkv, const float* __restrict__ kmax2,
    unsigned short* __restrict__ ohi, unsigned short* __restrict__ olo) {
  int b = blockIdx.x;
  int g = b >> 3;
  int h = (b >> 1) & 3;
  int half = b & 1;
  int t = threadIdx.x;
  int wave = t >> 6;
  int lane = t & 63;
  int quad = lane >> 4;
  int l15 = lane & 15;
  size_t gbase = (size_t)g * NPG;
  int qb = half * 256 + wave * 64;

  const float cf = 0.17677669529663687f * 1.4426950408889634f;  // scale*log2(e)

  __shared__ unsigned short Kh[32][36], Kl[32][36];
  __shared__ unsigned short Vh[33][36], Vl[33][36];
  __shared__ char wbuf[4][9472] __attribute__((aligned(16)));

  unsigned short* Ph = (unsigned short*)wbuf[wave];
  unsigned short* Pl = Ph + 64 * 36;
  float* Ot = (float*)wbuf[wave];

  bf16x8 qh[4], ql[4];
  float qn2p[4];
#pragma unroll
  for (int mt = 0; mt < 4; mt++) {
    const float* qp = &qkv[(gbase + qb + mt * 16 + l15) * 384 + h * 32 + quad * 8];
    float4 f0 = *(const float4*)qp;
    float4 f1 = *(const float4*)(qp + 4);
    float v[8] = {f0.x * cf, f0.y * cf, f0.z * cf, f0.w * cf,
                  f1.x * cf, f1.y * cf, f1.z * cf, f1.w * cf};
    u16x8 hh, ll;
    float s = 0.0f;
#pragma unroll
    for (int j = 0; j < 8; j++) {
      unsigned short hi_, lo_;
      split_bf(v[j], hi_, lo_);
      hh[j] = hi_;
      ll[j] = lo_;
      s = fmaf(v[j], v[j], s);
    }
    qh[mt] = __builtin_bit_cast(bf16x8, hh);
    ql[mt] = __builtin_bit_cast(bf16x8, ll);
    s += __shfl_xor(s, 16);
    s += __shfl_xor(s, 32);
    qn2p[mt] = s;
  }
  if (quad == 0) {
#pragma unroll
    for (int mt = 0; mt < 4; mt++) Ot[mt * 16 + l15] = qn2p[mt];
  }
  float km2 = kmax2[g * 4 + h];
  float Mq[4][4];
#pragma unroll
  for (int mt = 0; mt < 4; mt++)
#pragma unroll
    for (int r = 0; r < 4; r++)
      Mq[mt][r] = sqrtf(Ot[mt * 16 + quad * 4 + r] * km2);

  f32x4 Oa[4][3];
#pragma unroll
  for (int mt = 0; mt < 4; mt++)
#pragma unroll
    for (int nt = 0; nt < 3; nt++) Oa[mt][nt] = (f32x4)0.0f;

  for (int c = 0; c < 16; c++) {
    __syncthreads();
    if (t >= 128) {
      int t2 = t - 128;
      int key = t2 >> 2;
      int ds = (t2 & 3) * 8;
      const float* kp = &qkv[(gbase + (size_t)(c * 32 + key)) * 384 + 128 + h * 32 + ds];
      float4 f0 = *(const float4*)kp;
      float4 f1 = *(const float4*)(kp + 4);
      float v[8] = {f0.x, f0.y, f0.z, f0.w, f1.x, f1.y, f1.z, f1.w};
      u16x4 h0, h1, l0, l1;
#pragma unroll
      for (int j = 0; j < 4; j++) {
        unsigned short hi_, lo_;
        split_bf(v[j], hi_, lo_);
        h0[j] = hi_; l0[j] = lo_;
        split_bf(v[j + 4], hi_, lo_);
        h1[j] = hi_; l1[j] = lo_;
      }
      *(u16x4*)&Kh[key][ds] = h0;
      *(u16x4*)&Kh[key][ds + 4] = h1;
      *(u16x4*)&Kl[key][ds] = l0;
      *(u16x4*)&Kl[key][ds + 4] = l1;
    } else if (t < 64) {
      int keyb = (t & 7) * 4;
      int dvb = (t >> 3) * 4;
      float4 r0 = *(const float4*)&qkv[(gbase + (size_t)(c * 32 + keyb + 0)) * 384 + 256 + h * 32 + dvb];
      float4 r1 = *(const float4*)&qkv[(gbase + (size_t)(c * 32 + keyb + 1)) * 384 + 256 + h * 32 + dvb];
      float4 r2 = *(const float4*)&qkv[(gbase + (size_t)(c * 32 + keyb + 2)) * 384 + 256 + h * 32 + dvb];
      float4 r3 = *(const float4*)&qkv[(gbase + (size_t)(c * 32 + keyb + 3)) * 384 + 256 + h * 32 + dvb];
      float rr[4][4] = {{r0.x, r0.y, r0.z, r0.w}, {r1.x, r1.y, r1.z, r1.w},
                        {r2.x, r2.y, r2.z, r2.w}, {r3.x, r3.y, r3.z, r3.w}};
#pragma unroll
      for (int c2 = 0; c2 < 4; c2++) {
        ushort4 hv, lv;
        unsigned short hi_, lo_;
        split_bf(rr[0][c2], hi_, lo_); hv.x = hi_; lv.x = lo_;
        split_bf(rr[1][c2], hi_, lo_); hv.y = hi_; lv.y = lo_;
        split_bf(rr[2][c2], hi_, lo_); hv.z = hi_; lv.z = lo_;
        split_bf(rr[3][c2], hi_, lo_); hv.w = hi_; lv.w = lo_;
        *(ushort4*)&Vh[dvb + c2][keyb] = hv;
        *(ushort4*)&Vl[dvb + c2][keyb] = lv;
      }
    } else if (t < 68) {
      int i = t - 64;
      u16x8 ones;
#pragma unroll
      for (int j = 0; j < 8; j++) ones[j] = 0x3F80;
      *(u16x4*)&Vh[32][i * 8] = __builtin_shufflevector(ones, ones, 0, 1, 2, 3);
      *(u16x4*)&Vh[32][i * 8 + 4] = __builtin_shufflevector(ones, ones, 4, 5, 6, 7);
    }
    __syncthreads();

#pragma unroll
    for (int nt = 0; nt < 2; nt++) {
      bf16x8 bkh = ld_bf8(&Kh[nt * 16 + l15][quad * 8]);
      bf16x8 bkl = ld_bf8(&Kl[nt * 16 + l15][quad * 8]);
#pragma unroll
      for (int mt = 0; mt < 4; mt++) {
        f32x4 S = (f32x4)0.0f;
        S = __builtin_amdgcn_mfma_f32_16x16x32_bf16(qh[mt], bkh, S, 0, 0, 0);
        S = __builtin_amdgcn_mfma_f32_16x16x32_bf16(qh[mt], bkl, S, 0, 0, 0);
        S = __builtin_amdgcn_mfma_f32_16x16x32_bf16(ql[mt], bkh, S, 0, 0, 0);
#pragma unroll
        for (int r = 0; r < 4; r++) {
          float p = __builtin_exp2f(S[r] - Mq[mt][r]);
          unsigned short hi_, lo_;
          split_bf(p, hi_, lo_);
          int row = mt * 16 + quad * 4 + r;
          Ph[row * 36 + nt * 16 + l15] = hi_;
          Pl[row * 36 + nt * 16 + l15] = lo_;
        }
      }
    }
    bf16x8 pah[4], pal[4];
#pragma unroll
    for (int mt = 0; mt < 4; mt++) {
      pah[mt] = ld_bf8(&Ph[(mt * 16 + l15) * 36 + quad * 8]);
      pal[mt] = ld_bf8(&Pl[(mt * 16 + l15) * 36 + quad * 8]);
    }
#pragma unroll
    for (int nt = 0; nt < 3; nt++) {
      bf16x8 bvh = ld_bf8(&Vh[nt * 16 + l15][quad * 8]);
      if (nt < 2) {
        bf16x8 bvl = ld_bf8(&Vl[nt * 16 + l15][quad * 8]);
#pragma unroll
        for (int mt = 0; mt < 4; mt++) {
          Oa[mt][nt] = __builtin_amdgcn_mfma_f32_16x16x32_bf16(pah[mt], bvh, Oa[mt][nt], 0, 0, 0);
          Oa[mt][nt] = __builtin_amdgcn_mfma_f32_16x16x32_bf16(pah[mt], bvl, Oa[mt][nt], 0, 0, 0);
          Oa[mt][nt] = __builtin_amdgcn_mfma_f32_16x16x32_bf16(pal[mt], bvh, Oa[mt][nt], 0, 0, 0);
        }
      } else {
#pragma unroll
        for (int mt = 0; mt < 4; mt++) {
          Oa[mt][nt] = __builtin_amdgcn_mfma_f32_16x16x32_bf16(pah[mt], bvh, Oa[mt][nt], 0, 0, 0);
          Oa[mt][nt] = __builtin_amdgcn_mfma_f32_16x16x32_bf16(pal[mt], bvh, Oa[mt][nt], 0, 0, 0);
        }
      }
    }
  }

#pragma unroll
  for (int mt = 0; mt < 4; mt++) {
#pragma unroll
    for (int r = 0; r < 4; r++) {
      int row = mt * 16 + quad * 4 + r;
      Ot[row * 37 + l15] = Oa[mt][0][r];
      Ot[row * 37 + 16 + l15] = Oa[mt][1][r];
      if (l15 == 0) Ot[row * 37 + 32] = Oa[mt][2][r];
    }
  }
  {
    int row = lane;
    float inv = 1.0f / Ot[row * 37 + 32];
    size_t node = gbase + qb + row;
    u16x8 vh, vl;
#pragma unroll
    for (int seg = 0; seg < 4; seg++) {
#pragma unroll
      for (int j = 0; j < 8; j++) {
        unsigned short hi_, lo_;
        split_bf(Ot[row * 37 + seg * 8 + j] * inv, hi_, lo_);
        vh[j] = hi_;
        vl[j] = lo_;
      }
      *(u16x8*)(ohi + node * 128 + h * 32 + seg * 8) = vh;
      *(u16x8*)(olo + node * 128 + h * 32 + seg * 8) = vl;
    }
  }
}

// ---------------- mean pool ----------------
__global__ __launch_bounds__(128) void pool_kernel(const float* __restrict__ fin,
                                                   float* __restrict__ emb) {
  int g = blockIdx.x, c = threadIdx.x;
  const float* p = fin + (size_t)g * NPG * HID + c;
  float s = 0.0f;
  for (int i = 0; i < NPG; i++) s += p[(size_t)i * HID];
  emb[g * HID + c] = s * (1.0f / NPG);
}

extern "C" void kernel_launch(void* const* d_in, const int* in_sizes, int n_in,
                              void* d_out, int out_size, void* d_ws, size_t ws_size,
                              hipStream_t stream) {
  (void)in_sizes; (void)n_in; (void)out_size; (void)ws_size;
  const float* x          = (const float*)d_in[0];
  const float* W0         = (const float*)d_in[1];
  const float* b0         = (const float*)d_in[2];
  const float* Wh         = (const float*)d_in[3];
  const float* bh         = (const float*)d_in[4];
  const float* bn_gamma   = (const float*)d_in[5];
  const float* bn_beta    = (const float*)d_in[6];
  const float* bn_mean    = (const float*)d_in[7];
  const float* bn_var     = (const float*)d_in[8];
  const float* attn_in_w  = (const float*)d_in[9];
  const float* attn_in_b  = (const float*)d_in[10];
  const float* attn_out_w = (const float*)d_in[11];
  const float* attn_out_b = (const float*)d_in[12];
  const int* edge_index   = (const int*)d_in[13];
  const int* src = edge_index;
  const int* dst = edge_index + N_EDGES;

  char* ws = (char*)d_ws;
  size_t off = 0;
  auto alloc = [&](size_t bytes) -> void* {
    void* p = ws + off;
    off += (bytes + 255) & ~(size_t)255;
    return p;
  };
  int*   deg     = (int*)alloc((size_t)N_NODES * 4);
  int*   offsets = (int*)alloc((size_t)(N_NODES + 1) * 4);
  int*   cursor  = (int*)alloc((size_t)N_NODES * 4);
  int*   csr     = (int*)alloc((size_t)N_EDGES * 4);
  float* wedge   = (float*)alloc((size_t)N_EDGES * 4);
  float* dis     = (float*)alloc((size_t)N_NODES * 4);
  float* bufA    = (float*)alloc((size_t)N_NODES * HID * 4);   // layer features ping
  float* bufB    = (float*)alloc((size_t)N_NODES * HID * 4);   // layer features pong / f split
  unsigned short* zhi = (unsigned short*)alloc((size_t)N_NODES * HID * 2);  // attn o_hi
  unsigned short* zlo = (unsigned short*)alloc((size_t)N_NODES * HID * 2);  // attn o_lo
  float* qkvb    = (float*)alloc((size_t)N_NODES * 384 * 4);
  float* kmax2   = (float*)alloc((size_t)N_GRAPHS * 4 * 4);
  unsigned short* w0h = (unsigned short*)alloc(8192 * 2);
  unsigned short* w0l = (unsigned short*)alloc(8192 * 2);
  unsigned short* whh[3], *whl[3];
  for (int i = 0; i < 3; i++) {
    whh[i] = (unsigned short*)alloc(16384 * 2);
    whl[i] = (unsigned short*)alloc(16384 * 2);
  }
  unsigned short* wqh = (unsigned short*)alloc(49152 * 2);
  unsigned short* wql = (unsigned short*)alloc(49152 * 2);
  unsigned short* woh = (unsigned short*)alloc(16384 * 2);
  unsigned short* wol = (unsigned short*)alloc(16384 * 2);

  unsigned short* fhi = (unsigned short*)bufB;  // f split reuses bufB (dead after fused2)
  unsigned short* flo = fhi + (size_t)N_NODES * HID;

  float* fin = (float*)d_out;                       // [N, HID]
  float* emb = fin + (size_t)N_NODES * HID;         // [G, HID]

  hipMemsetAsync(deg, 0, (size_t)N_NODES * 4, stream);
  hist_kernel<<<N_EDGES / 256, 256, 0, stream>>>(dst, deg);
  dis_kernel<<<N_NODES / 256, 256, 0, stream>>>(deg, dis);
  scan_kernel<<<1, 1024, 0, stream>>>(deg, offsets, cursor);
  fill_kernel<<<N_EDGES / 256, 256, 0, stream>>>(src, dst, dis, cursor, csr, wedge);

  wprep_kernel<false><<<4, 256, 0, stream>>>(W0, 64, 128, w0h, w0l);
  for (int i = 0; i < 3; i++)
    wprep_kernel<false><<<8, 256, 0, stream>>>(Wh + (size_t)i * HID * HID, 128, 128,
                                               whh[i], whl[i]);
  wprep_kernel<true><<<24, 256, 0, stream>>>(attn_in_w, 128, 384, wqh, wql);
  wprep_kernel<true><<<8, 256, 0, stream>>>(attn_out_w, 128, 128, woh, wol);

  dim3 fgrid(N_NODES / 128, 1);
  // layer 0: x -> bufA
  fused_agg_gemm<64, 0><<<fgrid, 256, 0, stream>>>(
      x, dis, wedge, offsets, csr, w0h, w0l, b0,
      bn_gamma, bn_beta, bn_mean, bn_var, bufA, nullptr, nullptr);
  // layer 1: bufA -> bufB
  fused_agg_gemm<128, 0><<<fgrid, 256, 0, stream>>>(
      bufA, dis, wedge, offsets, csr, whh[0], whl[0], bh,
      bn_gamma + HID, bn_beta + HID, bn_mean + HID, bn_var + HID, bufB, nullptr, nullptr);
  // layer 2: bufB -> bufA
  fused_agg_gemm<128, 0><<<fgrid, 256, 0, stream>>>(
      bufB, dis, wedge, offsets, csr, whh[1], whl[1], bh + HID,
      bn_gamma + 2 * HID, bn_beta + 2 * HID, bn_mean + 2 * HID, bn_var + 2 * HID,
      bufA, nullptr, nullptr);
  // layer 3: bufA -> f split (into bufB region)
  fused_agg_gemm<128, 1><<<fgrid, 256, 0, stream>>>(
      bufA, dis, wedge, offsets, csr, whh[2], whl[2], bh + 2 * HID,
      bn_gamma + 3 * HID, bn_beta + 3 * HID, bn_mean + 3 * HID, bn_var + 3 * HID,
      nullptr, fhi, flo);
  // qkv = f @ attn_in_w^T + b
  dim3 qgrid(N_NODES / 128, 3);
  gemm_mfma<128, 384, false, false, 0><<<qgrid, 256, 0, stream>>>(
      fhi, flo, wqh, wql, attn_in_b, nullptr, nullptr, nullptr, nullptr,
      qkvb, nullptr, nullptr);
  knorm_kernel<<<N_GRAPHS * 4, 256, 0, stream>>>(qkvb, kmax2);
  attn_mfma_kernel<<<N_GRAPHS * 4 * 2, 256, 0, stream>>>(qkvb, kmax2, zhi, zlo);
  gemm_mfma<128, 128, false, false, 0><<<fgrid, 256, 0, stream>>>(
      zhi, zlo, woh, wol, attn_out_b, nullptr, nullptr, nullptr, nullptr,
      fin, nullptr, nullptr);
  pool_kernel<<<N_GRAPHS, 128, 0, stream>>>(fin, emb);
}

// Round 12
// 843.802 us; speedup vs baseline: 1.4579x; 1.1943x over previous
//
#include <hip/hip_runtime.h>
#include <hip/hip_bf16.h>
#include <cstdint>
#include <cstddef>

#define N_NODES 65536
#define N_EDGES 1048576
#define N_GRAPHS 128
#define NPG 512
#define IN_DIM 64
#define HID 128
#define BN_EPS 1e-5f

typedef __attribute__((ext_vector_type(8))) short bf16x8;
typedef __attribute__((ext_vector_type(8))) _Float16 f16x8;
typedef __attribute__((ext_vector_type(4))) float f32x4;
typedef __attribute__((ext_vector_type(8))) unsigned short u16x8;
typedef __attribute__((ext_vector_type(4))) unsigned short u16x4;

// ---- bf16 helpers (RNE, matches v_cvt) ----
__device__ inline unsigned short f2bf(float f) {
  unsigned u = __builtin_bit_cast(unsigned, f);
  u = u + 0x7fffu + ((u >> 16) & 1u);
  return (unsigned short)(u >> 16);
}
__device__ inline float bf2f(unsigned short h) {
  unsigned u = ((unsigned)h) << 16;
  return __builtin_bit_cast(float, u);
}
__device__ inline void split_bf(float v, unsigned short& hi, unsigned short& lo) {
  hi = f2bf(v);
  lo = f2bf(v - bf2f(hi));
}
// f16 split: 2x v_cvt + sub (cheaper than bf16 int math; pair = 21 mantissa bits)
__device__ inline void split_f16(float v, unsigned short& hi, unsigned short& lo) {
  _Float16 h = (_Float16)v;
  _Float16 l = (_Float16)(v - (float)h);
  hi = __builtin_bit_cast(unsigned short, h);
  lo = __builtin_bit_cast(unsigned short, l);
}
// 8-B-aligned LDS fragment loads (two ds_read_b64)
__device__ inline bf16x8 ld_bf8(const unsigned short* p) {
  u16x4 a = *(const u16x4*)p;
  u16x4 b = *(const u16x4*)(p + 4);
  u16x8 r = __builtin_shufflevector(a, b, 0, 1, 2, 3, 4, 5, 6, 7);
  return __builtin_bit_cast(bf16x8, r);
}
__device__ inline f16x8 ld_f16x8(const unsigned short* p) {
  u16x4 a = *(const u16x4*)p;
  u16x4 b = *(const u16x4*)(p + 4);
  u16x8 r = __builtin_shufflevector(a, b, 0, 1, 2, 3, 4, 5, 6, 7);
  return __builtin_bit_cast(f16x8, r);
}

// ---------------- CSR build ----------------
__global__ __launch_bounds__(256) void hist_kernel(const int* __restrict__ dst,
                                                   int* __restrict__ deg) {
  int e = blockIdx.x * 256 + threadIdx.x;
  if (e < N_EDGES) atomicAdd(&deg[dst[e]], 1);
}

__global__ __launch_bounds__(256) void dis_kernel(const int* __restrict__ deg,
                                                  float* __restrict__ dis) {
  int n = blockIdx.x * 256 + threadIdx.x;
  if (n < N_NODES) dis[n] = 1.0f / sqrtf((float)deg[n] + 1.0f);
}

__global__ __launch_bounds__(1024) void scan_kernel(const int* __restrict__ deg,
                                                    int* __restrict__ offsets,
                                                    int* __restrict__ cursor) {
  __shared__ int sums[1024];
  int t = threadIdx.x;
  int base = t * 64;
  const int4* dp = (const int4*)(deg + base);
  int s = 0;
#pragma unroll
  for (int i = 0; i < 16; i++) {
    int4 v = dp[i];
    s += v.x + v.y + v.z + v.w;
  }
  sums[t] = s;
  __syncthreads();
  for (int off = 1; off < 1024; off <<= 1) {
    int v = (t >= off) ? sums[t - off] : 0;
    __syncthreads();
    sums[t] += v;
    __syncthreads();
  }
  int run = (t == 0) ? 0 : sums[t - 1];
#pragma unroll
  for (int i = 0; i < 16; i++) {
    int4 v = dp[i];
    int idx = base + i * 4;
    offsets[idx] = run; cursor[idx] = run; run += v.x;
    offsets[idx + 1] = run; cursor[idx + 1] = run; run += v.y;
    offsets[idx + 2] = run; cursor[idx + 2] = run; run += v.z;
    offsets[idx + 3] = run; cursor[idx + 3] = run; run += v.w;
  }
  if (t == 1023) offsets[N_NODES] = run;
}

__global__ __launch_bounds__(256) void fill_kernel(const int* __restrict__ src,
                                                   const int* __restrict__ dst,
                                                   const float* __restrict__ dis,
                                                   int* __restrict__ cursor,
                                                   int* __restrict__ csr,
                                                   float* __restrict__ wedge) {
  int e = blockIdx.x * 256 + threadIdx.x;
  if (e < N_EDGES) {
    int d = dst[e];
    int s = src[e];
    int slot = atomicAdd(&cursor[d], 1);
    csr[slot] = s;
    wedge[slot] = dis[s] * dis[d];
  }
}

// ---------------- aggregation: wave-per-node, chunk-8 ILP (R9, proven) ----------------
__global__ __launch_bounds__(256) void agg64_kernel(const float* __restrict__ x,
                                                    const float* __restrict__ dis,
                                                    const float* __restrict__ wedge,
                                                    const int* __restrict__ offsets,
                                                    const int* __restrict__ csr,
                                                    unsigned short* __restrict__ zhi,
                                                    unsigned short* __restrict__ zlo) {
  int node = blockIdx.x * 4 + (threadIdx.x >> 6);
  int lane = threadIdx.x & 63;
  float dn = dis[node];
  float acc = x[(size_t)node * 64 + lane] * dn * dn;
  int beg = offsets[node], end = offsets[node + 1];
  int k = beg;
  for (; k + 8 <= end; k += 8) {
    int s[8];
    float w[8], v[8];
#pragma unroll
    for (int i = 0; i < 8; i++) {
      s[i] = csr[k + i];
      w[i] = wedge[k + i];
    }
#pragma unroll
    for (int i = 0; i < 8; i++) v[i] = x[(size_t)s[i] * 64 + lane];
#pragma unroll
    for (int i = 0; i < 8; i++) acc = fmaf(w[i], v[i], acc);
  }
  for (; k + 4 <= end; k += 4) {
    int s0 = csr[k], s1 = csr[k + 1], s2 = csr[k + 2], s3 = csr[k + 3];
    float w0 = wedge[k], w1 = wedge[k + 1], w2 = wedge[k + 2], w3 = wedge[k + 3];
    float v0 = x[(size_t)s0 * 64 + lane];
    float v1 = x[(size_t)s1 * 64 + lane];
    float v2 = x[(size_t)s2 * 64 + lane];
    float v3 = x[(size_t)s3 * 64 + lane];
    acc = fmaf(w0, v0, acc);
    acc = fmaf(w1, v1, acc);
    acc = fmaf(w2, v2, acc);
    acc = fmaf(w3, v3, acc);
  }
  for (; k < end; k++) {
    int s = csr[k];
    acc = fmaf(wedge[k], x[(size_t)s * 64 + lane], acc);
  }
  unsigned short h_, l_;
  split_bf(acc, h_, l_);
  zhi[(size_t)node * 64 + lane] = h_;
  zlo[(size_t)node * 64 + lane] = l_;
}

__global__ __launch_bounds__(256) void agg128_kernel(const float* __restrict__ h,
                                                     const float* __restrict__ dis,
                                                     const float* __restrict__ wedge,
                                                     const int* __restrict__ offsets,
                                                     const int* __restrict__ csr,
                                                     unsigned short* __restrict__ zhi,
                                                     unsigned short* __restrict__ zlo) {
  int node = blockIdx.x * 4 + (threadIdx.x >> 6);
  int lane = threadIdx.x & 63;
  float dn = dis[node];
  float sn = dn * dn;
  const float* hr = h + (size_t)node * 128;
  float a0 = hr[lane] * sn;
  float a1 = hr[lane + 64] * sn;
  int beg = offsets[node], end = offsets[node + 1];
  int k = beg;
  for (; k + 8 <= end; k += 8) {
    int s[8];
    float w[8], u[8], d[8];
#pragma unroll
    for (int i = 0; i < 8; i++) {
      s[i] = csr[k + i];
      w[i] = wedge[k + i];
    }
#pragma unroll
    for (int i = 0; i < 8; i++) {
      const float* p = h + (size_t)s[i] * 128;
      u[i] = p[lane];
      d[i] = p[lane + 64];
    }
#pragma unroll
    for (int i = 0; i < 8; i++) {
      a0 = fmaf(w[i], u[i], a0);
      a1 = fmaf(w[i], d[i], a1);
    }
  }
  for (; k + 4 <= end; k += 4) {
    int s0 = csr[k], s1 = csr[k + 1], s2 = csr[k + 2], s3 = csr[k + 3];
    float w0 = wedge[k], w1 = wedge[k + 1], w2 = wedge[k + 2], w3 = wedge[k + 3];
    const float* p0 = h + (size_t)s0 * 128;
    const float* p1 = h + (size_t)s1 * 128;
    const float* p2 = h + (size_t)s2 * 128;
    const float* p3 = h + (size_t)s3 * 128;
    float u0 = p0[lane], d0 = p0[lane + 64];
    float u1 = p1[lane], d1 = p1[lane + 64];
    float u2 = p2[lane], d2 = p2[lane + 64];
    float u3 = p3[lane], d3 = p3[lane + 64];
    a0 = fmaf(w0, u0, a0); a1 = fmaf(w0, d0, a1);
    a0 = fmaf(w1, u1, a0); a1 = fmaf(w1, d1, a1);
    a0 = fmaf(w2, u2, a0); a1 = fmaf(w2, d2, a1);
    a0 = fmaf(w3, u3, a0); a1 = fmaf(w3, d3, a1);
  }
  for (; k < end; k++) {
    int s = csr[k];
    float wt = wedge[k];
    const float* hs = h + (size_t)s * 128;
    a0 = fmaf(wt, hs[lane], a0);
    a1 = fmaf(wt, hs[lane + 64], a1);
  }
  unsigned short h0, l0, h1, l1;
  split_bf(a0, h0, l0);
  split_bf(a1, h1, l1);
  zhi[(size_t)node * 128 + lane] = h0;
  zlo[(size_t)node * 128 + lane] = l0;
  zhi[(size_t)node * 128 + lane + 64] = h1;
  zlo[(size_t)node * 128 + lane + 64] = l1;
}

// ---------------- weight prep: fp32 W -> bf16 hi/lo in b-fragment layout ----------------
template <bool TRANS>
__global__ __launch_bounds__(256) void wprep_kernel(const float* __restrict__ W, int K, int O,
                                                    unsigned short* __restrict__ hi,
                                                    unsigned short* __restrict__ lo) {
  int idx = blockIdx.x * 256 + threadIdx.x;
  int KC = K / 32;
  int total = (O / 16) * KC * 64;
  if (idx >= total) return;
  int lane = idx & 63;
  int rest = idx >> 6;
  int kc = rest % KC;
  int nt = rest / KC;
  int n = nt * 16 + (lane & 15);
  int kb = kc * 32 + (lane >> 4) * 8;
  unsigned short* hp = hi + (size_t)idx * 8;
  unsigned short* lp = lo + (size_t)idx * 8;
#pragma unroll
  for (int j = 0; j < 8; j++) {
    int k = kb + j;
    float v = TRANS ? W[(size_t)n * K + k] : W[(size_t)k * O + n];
    unsigned short h_, l_;
    split_bf(v, h_, l_);
    hp[j] = h_;
    lp[j] = l_;
  }
}

// ---------------- MFMA GEMM (3 split-products). OUTMODE: 0=f32 rows, 1=bf16 split,
// 3=f16 split planes (feeds f16 attention) ----------------
template <int K, int O, bool DOBN, bool DORELU, int OUTMODE>
__global__ __launch_bounds__(256) void gemm_mfma(
    const unsigned short* __restrict__ Ahi, const unsigned short* __restrict__ Alo,
    const unsigned short* __restrict__ Whi, const unsigned short* __restrict__ Wlo,
    const float* __restrict__ bias,
    const float* __restrict__ gamma, const float* __restrict__ beta,
    const float* __restrict__ mean, const float* __restrict__ var,
    float* __restrict__ Cf, unsigned short* __restrict__ Chi,
    unsigned short* __restrict__ Clo) {
  constexpr int KC = K / 32;
  int wave = threadIdx.x >> 6;
  int lane = threadIdx.x & 63;
  int m0 = blockIdx.x * 128 + wave * 32;
  int o0 = blockIdx.y * 128;
  int mrow = lane & 15;
  int kseg = (lane >> 4) * 8;

  f32x4 acc[2][8];
#pragma unroll
  for (int mt = 0; mt < 2; mt++)
#pragma unroll
    for (int nt = 0; nt < 8; nt++) acc[mt][nt] = (f32x4)0.0f;

#pragma unroll
  for (int kc = 0; kc < KC; kc++) {
    bf16x8 ah[2], al[2];
#pragma unroll
    for (int mt = 0; mt < 2; mt++) {
      size_t aoff = (size_t)(m0 + mt * 16 + mrow) * K + kc * 32 + kseg;
      ah[mt] = *(const bf16x8*)(Ahi + aoff);
      al[mt] = *(const bf16x8*)(Alo + aoff);
    }
#pragma unroll
    for (int nt = 0; nt < 8; nt++) {
      size_t foff = (((size_t)(blockIdx.y * 8 + nt) * KC + kc) * 64 + lane) * 8;
      bf16x8 bh = *(const bf16x8*)(Whi + foff);
      bf16x8 bl = *(const bf16x8*)(Wlo + foff);
#pragma unroll
      for (int mt = 0; mt < 2; mt++) {
        acc[mt][nt] = __builtin_amdgcn_mfma_f32_16x16x32_bf16(ah[mt], bh, acc[mt][nt], 0, 0, 0);
        acc[mt][nt] = __builtin_amdgcn_mfma_f32_16x16x32_bf16(ah[mt], bl, acc[mt][nt], 0, 0, 0);
        acc[mt][nt] = __builtin_amdgcn_mfma_f32_16x16x32_bf16(al[mt], bh, acc[mt][nt], 0, 0, 0);
      }
    }
  }

  int ccol = lane & 15;
  int crow0 = (lane >> 4) * 4;
#pragma unroll
  for (int nt = 0; nt < 8; nt++) {
    int c = o0 + nt * 16 + ccol;
    float sc, cb;
    float b = bias[c];
    if (DOBN) {
      sc = gamma[c] * rsqrtf(var[c] + BN_EPS);
      cb = (b - mean[c]) * sc + beta[c];
    } else {
      sc = 1.0f;
      cb = b;
    }
#pragma unroll
    for (int mt = 0; mt < 2; mt++) {
#pragma unroll
      for (int r = 0; r < 4; r++) {
        float v = fmaf(acc[mt][nt][r], sc, cb);
        if (DORELU) v = fmaxf(v, 0.0f);
        size_t row = (size_t)(m0 + mt * 16 + crow0 + r);
        if (OUTMODE == 1) {
          unsigned short h_, l_;
          split_bf(v, h_, l_);
          Chi[row * O + c] = h_;
          Clo[row * O + c] = l_;
        } else if (OUTMODE == 3) {
          unsigned short h_, l_;
          split_f16(v, h_, l_);
          Chi[row * O + c] = h_;
          Clo[row * O + c] = l_;
        } else {
          Cf[row * O + c] = v;
        }
      }
    }
  }
}

// ---------------- key-norm max per (graph, head), from f16 split planes ----------------
__global__ __launch_bounds__(256) void knorm_kernel(const unsigned short* __restrict__ qsh,
                                                    const unsigned short* __restrict__ qsl,
                                                    float* __restrict__ kmax2) {
  int g = blockIdx.x >> 2;
  int h = blockIdx.x & 3;
  size_t gbase = (size_t)g * NPG;
  float best = 0.0f;
#pragma unroll
  for (int r = 0; r < 2; r++) {
    int j = r * 256 + threadIdx.x;
    size_t base = (gbase + j) * 384 + 128 + h * 32;
    float s = 0.0f;
#pragma unroll
    for (int i = 0; i < 4; i++) {
      f16x8 hv = ld_f16x8(qsh + base + i * 8);  // global, but ld pattern is fine
      f16x8 lv = ld_f16x8(qsl + base + i * 8);
#pragma unroll
      for (int q = 0; q < 8; q++) {
        float kvf = (float)hv[q] + (float)lv[q];
        s = fmaf(kvf, kvf, s);
      }
    }
    best = fmaxf(best, s);
  }
#pragma unroll
  for (int off = 32; off >= 1; off >>= 1)
    best = fmaxf(best, __shfl_xor(best, off, 64));
  __shared__ float red[4];
  int wave = threadIdx.x >> 6;
  if ((threadIdx.x & 63) == 0) red[wave] = best;
  __syncthreads();
  if (threadIdx.x == 0) {
    float m = fmaxf(fmaxf(red[0], red[1]), fmaxf(red[2], red[3]));
    kmax2[blockIdx.x] = m;
  }
}

// ---------------- attention via f16 MFMA, pre-split qkv planes ----------------
// R8 structure; R12: qkv arrives as f16 hi/lo planes -> staging is pure u16 copies
// (no splits); arithmetic in f16 (split = 2 cvt + sub); scale folded into exp2 arg.
__global__ __launch_bounds__(256, 2) void attn_mfma_kernel(
    const unsigned short* __restrict__ qsh, const unsigned short* __restrict__ qsl,
    const float* __restrict__ kmax2,
    unsigned short* __restrict__ ohi, unsigned short* __restrict__ olo) {
  int b = blockIdx.x;
  int g = b >> 3;
  int h = (b >> 1) & 3;
  int half = b & 1;
  int t = threadIdx.x;
  int wave = t >> 6;
  int lane = t & 63;
  int quad = lane >> 4;
  int l15 = lane & 15;
  size_t gbase = (size_t)g * NPG;
  int qb = half * 256 + wave * 64;

  const float cfl = 0.17677669529663687f * 1.4426950408889634f;  // scale*log2(e)

  __shared__ unsigned short Kh[32][36], Kl[32][36];
  __shared__ unsigned short Vh[33][36], Vl[33][36];
  __shared__ char wbuf[4][9472] __attribute__((aligned(16)));

  unsigned short* Ph = (unsigned short*)wbuf[wave];
  unsigned short* Pl = Ph + 64 * 36;
  float* Ot = (float*)wbuf[wave];

  // ---- Q fragments: direct loads from pre-split planes; qn2 via reconstruction ----
  f16x8 qh[4], ql[4];
  float qn2p[4];
#pragma unroll
  for (int mt = 0; mt < 4; mt++) {
    size_t base = (gbase + qb + mt * 16 + l15) * 384 + h * 32 + quad * 8;
    u16x8 hu = *(const u16x8*)(qsh + base);
    u16x8 lu = *(const u16x8*)(qsl + base);
    qh[mt] = __builtin_bit_cast(f16x8, hu);
    ql[mt] = __builtin_bit_cast(f16x8, lu);
    float s = 0.0f;
#pragma unroll
    for (int j = 0; j < 8; j++) {
      float q = (float)qh[mt][j] + (float)ql[mt][j];
      s = fmaf(q, q, s);
    }
    s += __shfl_xor(s, 16);
    s += __shfl_xor(s, 32);
    qn2p[mt] = s;
  }
  if (quad == 0) {
#pragma unroll
    for (int mt = 0; mt < 4; mt++) Ot[mt * 16 + l15] = qn2p[mt];
  }
  float km2 = kmax2[g * 4 + h];
  float Mq[4][4];
#pragma unroll
  for (int mt = 0; mt < 4; mt++)
#pragma unroll
    for (int r = 0; r < 4; r++)
      Mq[mt][r] = cfl * sqrtf(Ot[mt * 16 + quad * 4 + r] * km2);  // >= cfl*max(q.k)

  f32x4 Oa[4][3];
#pragma unroll
  for (int mt = 0; mt < 4; mt++)
#pragma unroll
    for (int nt = 0; nt < 3; nt++) Oa[mt][nt] = (f32x4)0.0f;

  for (int c = 0; c < 16; c++) {
    __syncthreads();
    if (t >= 128) {
      // stage K rows: pure u16 copies
      int t2 = t - 128;
      int key = t2 >> 2;
      int ds = (t2 & 3) * 8;
      size_t base = (gbase + (size_t)(c * 32 + key)) * 384 + 128 + h * 32 + ds;
      u16x8 hu = *(const u16x8*)(qsh + base);
      u16x8 lu = *(const u16x8*)(qsl + base);
      *(u16x4*)&Kh[key][ds] = __builtin_shufflevector(hu, hu, 0, 1, 2, 3);
      *(u16x4*)&Kh[key][ds + 4] = __builtin_shufflevector(hu, hu, 4, 5, 6, 7);
      *(u16x4*)&Kl[key][ds] = __builtin_shufflevector(lu, lu, 0, 1, 2, 3);
      *(u16x4*)&Kl[key][ds + 4] = __builtin_shufflevector(lu, lu, 4, 5, 6, 7);
    } else if (t < 64) {
      // stage V^T 4x4 u16 blocks: copies + transpose
      int keyb = (t & 7) * 4;
      int dvb = (t >> 3) * 4;
      u16x4 h0, h1, h2, h3, l0, l1, l2, l3;
      {
        size_t r0 = (gbase + (size_t)(c * 32 + keyb + 0)) * 384 + 256 + h * 32 + dvb;
        size_t r1 = (gbase + (size_t)(c * 32 + keyb + 1)) * 384 + 256 + h * 32 + dvb;
        size_t r2 = (gbase + (size_t)(c * 32 + keyb + 2)) * 384 + 256 + h * 32 + dvb;
        size_t r3 = (gbase + (size_t)(c * 32 + keyb + 3)) * 384 + 256 + h * 32 + dvb;
        h0 = *(const u16x4*)(qsh + r0); l0 = *(const u16x4*)(qsl + r0);
        h1 = *(const u16x4*)(qsh + r1); l1 = *(const u16x4*)(qsl + r1);
        h2 = *(const u16x4*)(qsh + r2); l2 = *(const u16x4*)(qsl + r2);
        h3 = *(const u16x4*)(qsh + r3); l3 = *(const u16x4*)(qsl + r3);
      }
#pragma unroll
      for (int c2 = 0; c2 < 4; c2++) {
        u16x4 hv = {h0[c2], h1[c2], h2[c2], h3[c2]};
        u16x4 lv = {l0[c2], l1[c2], l2[c2], l3[c2]};
        *(u16x4*)&Vh[dvb + c2][keyb] = hv;
        *(u16x4*)&Vl[dvb + c2][keyb] = lv;
      }
    } else if (t < 68) {
      int i = t - 64;
      u16x4 ones = {0x3C00, 0x3C00, 0x3C00, 0x3C00};  // f16 1.0
      *(u16x4*)&Vh[32][i * 8] = ones;
      *(u16x4*)&Vh[32][i * 8 + 4] = ones;
    }
    __syncthreads();

    // ---- QK^T -> S -> P (f16, 3 split-products; scale folded into exp2 arg) ----
#pragma unroll
    for (int nt = 0; nt < 2; nt++) {
      f16x8 bkh = ld_f16x8(&Kh[nt * 16 + l15][quad * 8]);
      f16x8 bkl = ld_f16x8(&Kl[nt * 16 + l15][quad * 8]);
#pragma unroll
      for (int mt = 0; mt < 4; mt++) {
        f32x4 S = (f32x4)0.0f;
        S = __builtin_amdgcn_mfma_f32_16x16x32_f16(qh[mt], bkh, S, 0, 0, 0);
        S = __builtin_amdgcn_mfma_f32_16x16x32_f16(qh[mt], bkl, S, 0, 0, 0);
        S = __builtin_amdgcn_mfma_f32_16x16x32_f16(ql[mt], bkh, S, 0, 0, 0);
#pragma unroll
        for (int r = 0; r < 4; r++) {
          float p = __builtin_exp2f(fmaf(S[r], cfl, -Mq[mt][r]));
          unsigned short hi_, lo_;
          split_f16(p, hi_, lo_);
          int row = mt * 16 + quad * 4 + r;
          Ph[row * 36 + nt * 16 + l15] = hi_;
          Pl[row * 36 + nt * 16 + l15] = lo_;
        }
      }
    }
    // ---- PV (f16) ----
    f16x8 pah[4], pal[4];
#pragma unroll
    for (int mt = 0; mt < 4; mt++) {
      pah[mt] = ld_f16x8(&Ph[(mt * 16 + l15) * 36 + quad * 8]);
      pal[mt] = ld_f16x8(&Pl[(mt * 16 + l15) * 36 + quad * 8]);
    }
#pragma unroll
    for (int nt = 0; nt < 3; nt++) {
      f16x8 bvh = ld_f16x8(&Vh[nt * 16 + l15][quad * 8]);
      if (nt < 2) {
        f16x8 bvl = ld_f16x8(&Vl[nt * 16 + l15][quad * 8]);
#pragma unroll
        for (int mt = 0; mt < 4; mt++) {
          Oa[mt][nt] = __builtin_amdgcn_mfma_f32_16x16x32_f16(pah[mt], bvh, Oa[mt][nt], 0, 0, 0);
          Oa[mt][nt] = __builtin_amdgcn_mfma_f32_16x16x32_f16(pah[mt], bvl, Oa[mt][nt], 0, 0, 0);
          Oa[mt][nt] = __builtin_amdgcn_mfma_f32_16x16x32_f16(pal[mt], bvh, Oa[mt][nt], 0, 0, 0);
        }
      } else {
#pragma unroll
        for (int mt = 0; mt < 4; mt++) {
          Oa[mt][nt] = __builtin_amdgcn_mfma_f32_16x16x32_f16(pah[mt], bvh, Oa[mt][nt], 0, 0, 0);
          Oa[mt][nt] = __builtin_amdgcn_mfma_f32_16x16x32_f16(pal[mt], bvh, Oa[mt][nt], 0, 0, 0);
        }
      }
    }
  }

  // ---- epilogue: transpose O through per-wave LDS (stride 37), normalize, store ----
#pragma unroll
  for (int mt = 0; mt < 4; mt++) {
#pragma unroll
    for (int r = 0; r < 4; r++) {
      int row = mt * 16 + quad * 4 + r;
      Ot[row * 37 + l15] = Oa[mt][0][r];
      Ot[row * 37 + 16 + l15] = Oa[mt][1][r];
      if (l15 == 0) Ot[row * 37 + 32] = Oa[mt][2][r];
    }
  }
  {
    int row = lane;
    float inv = 1.0f / Ot[row * 37 + 32];
    size_t node = gbase + qb + row;
    u16x8 vh, vl;
#pragma unroll
    for (int seg = 0; seg < 4; seg++) {
#pragma unroll
      for (int j = 0; j < 8; j++) {
        unsigned short hi_, lo_;
        split_bf(Ot[row * 37 + seg * 8 + j] * inv, hi_, lo_);
        vh[j] = hi_;
        vl[j] = lo_;
      }
      *(u16x8*)(ohi + node * 128 + h * 32 + seg * 8) = vh;
      *(u16x8*)(olo + node * 128 + h * 32 + seg * 8) = vl;
    }
  }
}

// ---------------- mean pool ----------------
__global__ __launch_bounds__(128) void pool_kernel(const float* __restrict__ fin,
                                                   float* __restrict__ emb) {
  int g = blockIdx.x, c = threadIdx.x;
  const float* p = fin + (size_t)g * NPG * HID + c;
  float s = 0.0f;
  for (int i = 0; i < NPG; i++) s += p[(size_t)i * HID];
  emb[g * HID + c] = s * (1.0f / NPG);
}

extern "C" void kernel_launch(void* const* d_in, const int* in_sizes, int n_in,
                              void* d_out, int out_size, void* d_ws, size_t ws_size,
                              hipStream_t stream) {
  (void)in_sizes; (void)n_in; (void)out_size; (void)ws_size;
  const float* x          = (const float*)d_in[0];
  const float* W0         = (const float*)d_in[1];
  const float* b0         = (const float*)d_in[2];
  const float* Wh         = (const float*)d_in[3];
  const float* bh         = (const float*)d_in[4];
  const float* bn_gamma   = (const float*)d_in[5];
  const float* bn_beta    = (const float*)d_in[6];
  const float* bn_mean    = (const float*)d_in[7];
  const float* bn_var     = (const float*)d_in[8];
  const float* attn_in_w  = (const float*)d_in[9];
  const float* attn_in_b  = (const float*)d_in[10];
  const float* attn_out_w = (const float*)d_in[11];
  const float* attn_out_b = (const float*)d_in[12];
  const int* edge_index   = (const int*)d_in[13];
  const int* src = edge_index;
  const int* dst = edge_index + N_EDGES;

  char* ws = (char*)d_ws;
  size_t off = 0;
  auto alloc = [&](size_t bytes) -> void* {
    void* p = ws + off;
    off += (bytes + 255) & ~(size_t)255;
    return p;
  };
  int*   deg     = (int*)alloc((size_t)N_NODES * 4);
  int*   offsets = (int*)alloc((size_t)(N_NODES + 1) * 4);
  int*   cursor  = (int*)alloc((size_t)N_NODES * 4);
  int*   csr     = (int*)alloc((size_t)N_EDGES * 4);
  float* wedge   = (float*)alloc((size_t)N_EDGES * 4);
  float* dis     = (float*)alloc((size_t)N_NODES * 4);
  float* bufA    = (float*)alloc((size_t)N_NODES * HID * 4);   // h fp32; later f_hi/f_lo
  unsigned short* zhi = (unsigned short*)alloc((size_t)N_NODES * HID * 2);  // also o_hi
  unsigned short* zlo = (unsigned short*)alloc((size_t)N_NODES * HID * 2);  // also o_lo
  unsigned short* qsh = (unsigned short*)alloc((size_t)N_NODES * 384 * 2);  // qkv f16 hi
  unsigned short* qsl = (unsigned short*)alloc((size_t)N_NODES * 384 * 2);  // qkv f16 lo
  float* kmax2   = (float*)alloc((size_t)N_GRAPHS * 4 * 4);
  unsigned short* w0h = (unsigned short*)alloc(8192 * 2);
  unsigned short* w0l = (unsigned short*)alloc(8192 * 2);
  unsigned short* whh[3], *whl[3];
  for (int i = 0; i < 3; i++) {
    whh[i] = (unsigned short*)alloc(16384 * 2);
    whl[i] = (unsigned short*)alloc(16384 * 2);
  }
  unsigned short* wqh = (unsigned short*)alloc(49152 * 2);
  unsigned short* wql = (unsigned short*)alloc(49152 * 2);
  unsigned short* woh = (unsigned short*)alloc(16384 * 2);
  unsigned short* wol = (unsigned short*)alloc(16384 * 2);

  unsigned short* fhi = (unsigned short*)bufA;   // f split reuses bufA
  unsigned short* flo = fhi + (size_t)N_NODES * HID;

  float* fin = (float*)d_out;                       // [N, HID]
  float* emb = fin + (size_t)N_NODES * HID;         // [G, HID]

  hipMemsetAsync(deg, 0, (size_t)N_NODES * 4, stream);
  hist_kernel<<<N_EDGES / 256, 256, 0, stream>>>(dst, deg);
  dis_kernel<<<N_NODES / 256, 256, 0, stream>>>(deg, dis);
  scan_kernel<<<1, 1024, 0, stream>>>(deg, offsets, cursor);
  fill_kernel<<<N_EDGES / 256, 256, 0, stream>>>(src, dst, dis, cursor, csr, wedge);

  wprep_kernel<false><<<4, 256, 0, stream>>>(W0, 64, 128, w0h, w0l);
  for (int i = 0; i < 3; i++)
    wprep_kernel<false><<<8, 256, 0, stream>>>(Wh + (size_t)i * HID * HID, 128, 128,
                                               whh[i], whl[i]);
  wprep_kernel<true><<<24, 256, 0, stream>>>(attn_in_w, 128, 384, wqh, wql);
  wprep_kernel<true><<<8, 256, 0, stream>>>(attn_out_w, 128, 128, woh, wol);

  dim3 ggrid(N_NODES / 128, 1);
  agg64_kernel<<<N_NODES / 4, 256, 0, stream>>>(x, dis, wedge, offsets, csr, zhi, zlo);
  gemm_mfma<64, 128, true, true, 0><<<ggrid, 256, 0, stream>>>(
      zhi, zlo, w0h, w0l, b0, bn_gamma, bn_beta, bn_mean, bn_var, bufA, nullptr, nullptr);
  for (int L = 0; L < 2; L++) {
    agg128_kernel<<<N_NODES / 4, 256, 0, stream>>>(bufA, dis, wedge, offsets, csr, zhi, zlo);
    gemm_mfma<128, 128, true, true, 0><<<ggrid, 256, 0, stream>>>(
        zhi, zlo, whh[L], whl[L], bh + (size_t)L * HID,
        bn_gamma + (size_t)(L + 1) * HID, bn_beta + (size_t)(L + 1) * HID,
        bn_mean + (size_t)(L + 1) * HID, bn_var + (size_t)(L + 1) * HID,
        bufA, nullptr, nullptr);
  }
  agg128_kernel<<<N_NODES / 4, 256, 0, stream>>>(bufA, dis, wedge, offsets, csr, zhi, zlo);
  gemm_mfma<128, 128, true, true, 1><<<ggrid, 256, 0, stream>>>(
      zhi, zlo, whh[2], whl[2], bh + (size_t)2 * HID,
      bn_gamma + (size_t)3 * HID, bn_beta + (size_t)3 * HID,
      bn_mean + (size_t)3 * HID, bn_var + (size_t)3 * HID,
      nullptr, fhi, flo);
  // qkv = f @ attn_in_w^T + b  -> f16 split planes
  dim3 qgrid(N_NODES / 128, 3);
  gemm_mfma<128, 384, false, false, 3><<<qgrid, 256, 0, stream>>>(
      fhi, flo, wqh, wql, attn_in_b, nullptr, nullptr, nullptr, nullptr,
      nullptr, qsh, qsl);
  knorm_kernel<<<N_GRAPHS * 4, 256, 0, stream>>>(qsh, qsl, kmax2);
  attn_mfma_kernel<<<N_GRAPHS * 4 * 2, 256, 0, stream>>>(qsh, qsl, kmax2, zhi, zlo);
  gemm_mfma<128, 128, false, false, 0><<<ggrid, 256, 0, stream>>>(
      zhi, zlo, woh, wol, attn_out_b, nullptr, nullptr, nullptr, nullptr,
      fin, nullptr, nullptr);
  pool_kernel<<<N_GRAPHS, 128, 0, stream>>>(fin, emb);
}